// Round 6
// baseline (153.661 us; speedup 1.0000x reference)
//
#include <hip/hip_runtime.h>

// Problem constants (fixed by setup_inputs)
#define NNODES 27648
#define NEDGES 442368
#define FIN    256
#define HC     512
#define NH     4
#define CDIM   128
#define NAG    48
#define NGRP   12
#define N2     2304    // 48*48
#define NOUT   576     // 12*48
#define CAP    128     // max edges kept per output row (Poisson mean ~16)
#define EDIM   16
#define MPART  512     // meansum partial blocks
#define SCANB  (NEDGES/256)   // 1728 edge-scan blocks
#define ASRCB0 (SCANB + 1)    // first asrc block in k_scan

// R6: precompute a_src/a_dst for ALL nodes (fused into k_scan, wave-per-node,
// coalesced x reads). k_mega's logit phase becomes thread-per-edge 16B lookups
// (no x loads, no wave reductions). Gemm tail unchanged from R5 (2 rows/block,
// weight loads shared across rows).

__device__ __forceinline__ float lrelu(float v, float s){ return v > 0.0f ? v : s * v; }

__device__ __forceinline__ float wsum(float v){
  #pragma unroll
  for (int off = 32; off; off >>= 1) v += __shfl_xor(v, off, 64);
  return v;
}
__device__ __forceinline__ float wmax(float v){
  #pragma unroll
  for (int off = 32; off; off >>= 1) v = fmaxf(v, __shfl_xor(v, off, 64));
  return v;
}

// K_A (fused): blocks 0..10  -> ws/wd/we precompute + zero counts
//              blocks 11..   -> edge_attr column partial sums (float4, grid-stride)
__global__ __launch_bounds__(256) void k_pre(
    const float* __restrict__ W, const float* __restrict__ att_src,
    const float* __restrict__ att_dst, const float* __restrict__ W_edge,
    const float* __restrict__ att_edge, const float* __restrict__ ea,
    float* __restrict__ ws_, float* __restrict__ wd_, float* __restrict__ we_,
    int* __restrict__ counts, float4* __restrict__ easum_part){
  int b = blockIdx.x;
  int tid = threadIdx.x;
  if (b < 11) {
    int g = b * 256 + tid;
    if (g < 1024) {
      int f = g >> 2, h = g & 3;
      const float4* wp = (const float4*)(W + f*HC + h*CDIM);
      const float4* ap = (const float4*)(att_src + h*CDIM);
      float s = 0.f;
      #pragma unroll 8
      for (int c4 = 0; c4 < CDIM/4; c4++){
        float4 wv = wp[c4], av = ap[c4];
        s += wv.x*av.x + wv.y*av.y + wv.z*av.z + wv.w*av.w;
      }
      ws_[g] = s;
    } else if (g < 2048) {
      int gg = g - 1024; int f = gg >> 2, h = gg & 3;
      const float4* wp = (const float4*)(W + f*HC + h*CDIM);
      const float4* ap = (const float4*)(att_dst + h*CDIM);
      float s = 0.f;
      #pragma unroll 8
      for (int c4 = 0; c4 < CDIM/4; c4++){
        float4 wv = wp[c4], av = ap[c4];
        s += wv.x*av.x + wv.y*av.y + wv.z*av.z + wv.w*av.w;
      }
      wd_[gg] = s;
    } else if (g < 2112) {
      int gg = g - 2048; int d = gg >> 2, h = gg & 3;
      const float4* wp = (const float4*)(W_edge + d*HC + h*CDIM);
      const float4* ap = (const float4*)(att_edge + h*CDIM);
      float s = 0.f;
      #pragma unroll 8
      for (int c4 = 0; c4 < CDIM/4; c4++){
        float4 wv = wp[c4], av = ap[c4];
        s += wv.x*av.x + wv.y*av.y + wv.z*av.z + wv.w*av.w;
      }
      we_[gg] = s;
    } else if (g < 2112 + NOUT) {
      counts[g - 2112] = 0;
    }
  } else {
    // edge_attr partial column sums; col-group = idx & 3 (invariant under stride)
    int pb = b - 11;
    const float4* p = (const float4*)ea;
    const int total = NEDGES * 4;           // float4 count
    float4 acc = make_float4(0.f, 0.f, 0.f, 0.f);
    for (int i = pb*256 + tid; i < total; i += MPART*256){
      float4 v = p[i];
      acc.x += v.x; acc.y += v.y; acc.z += v.z; acc.w += v.w;
    }
    // reduce across the 16 lanes sharing lane&3
    #pragma unroll
    for (int off = 4; off <= 32; off <<= 1){
      acc.x += __shfl_xor(acc.x, off, 64);
      acc.y += __shfl_xor(acc.y, off, 64);
      acc.z += __shfl_xor(acc.z, off, 64);
      acc.w += __shfl_xor(acc.w, off, 64);
    }
    __shared__ float4 sd4[16];
    int lane = tid & 63, wave = tid >> 6;
    if (lane < 4) sd4[wave*4 + lane] = acc;
    __syncthreads();
    if (tid < 4){
      float4 t = sd4[tid];
      float4 a = sd4[4+tid], c = sd4[8+tid], d = sd4[12+tid];
      t.x += a.x + c.x + d.x; t.y += a.y + c.y + d.y;
      t.z += a.z + c.z + d.z; t.w += a.w + c.w + d.w;
      easum_part[pb*4 + tid] = t;
    }
  }
}

// K_B (fused): blocks 0..1727   bin edges whose dst is diagonal
//              block 1728       reduce easum + compute mal (self-loop edge logit)
//              blocks 1729..    a_src/a_dst for all nodes (wave per node)
__global__ __launch_bounds__(256) void k_scan(const int* __restrict__ ei,
    const float* __restrict__ ea, const float* __restrict__ we_,
    const float* __restrict__ ws_, const float* __restrict__ wd_,
    const float* __restrict__ x,
    int* __restrict__ counts, int* __restrict__ slist, float* __restrict__ aed,
    const float* __restrict__ easum_part, float* __restrict__ easum,
    float* __restrict__ mal, float* __restrict__ asrc, float* __restrict__ adst){
  int tid = threadIdx.x;
  int b = blockIdx.x;
  if (b < SCANB){
    int e = b*256 + tid;
    int dst = ei[NEDGES + e];
    int r = dst % N2;
    if (r % 49) return;
    int row = (dst / N2) * NAG + r / 49;
    int pos = atomicAdd(&counts[row], 1);
    if (pos >= CAP) return;
    slist[row*CAP + pos] = ei[e];
    const float* eap = ea + (size_t)e*EDIM;
    float a0=0.f,a1=0.f,a2=0.f,a3=0.f;
    #pragma unroll
    for (int d = 0; d < EDIM; d++){
      float v = eap[d];
      a0 += v*we_[d*4+0]; a1 += v*we_[d*4+1]; a2 += v*we_[d*4+2]; a3 += v*we_[d*4+3];
    }
    float* ap = aed + (size_t)(row*CAP+pos)*4;
    ap[0]=a0; ap[1]=a1; ap[2]=a2; ap[3]=a3;
    return;
  }
  if (b == SCANB){
    // reduce 512 partial blocks x 16 cols -> easum[16]; then mal[4]
    int col = tid & 15, part = tid >> 4;          // 16 parts x 32 pblocks
    float s = 0.f;
    for (int pb = 0; pb < MPART/16; pb++)
      s += easum_part[(part*(MPART/16) + pb)*16 + col];
    __shared__ float sd[256];
    __shared__ float se[16];
    sd[tid] = s;
    __syncthreads();
    if (tid < 16){
      float t = 0.f;
      #pragma unroll
      for (int i = 0; i < 16; i++) t += sd[i*16 + tid];
      easum[tid] = t;
      se[tid] = t;
    }
    __syncthreads();
    if (tid < 4){
      const float invE = 1.0f/(float)NEDGES;
      float m = 0.f;
      #pragma unroll
      for (int d = 0; d < 16; d++) m += se[d]*invE*we_[d*4+tid];
      mal[tid] = m;
    }
    return;
  }
  // a_src / a_dst precompute: one wave per node, coalesced 1KB x-row read
  {
    int lane = tid & 63, wave = tid >> 6;
    int node = (b - ASRCB0)*4 + wave;
    float4 xv = *(const float4*)(x + (size_t)node*FIN + lane*4);
    float ps[4] = {0.f,0.f,0.f,0.f}, pd[4] = {0.f,0.f,0.f,0.f};
    #pragma unroll
    for (int q = 0; q < 4; q++){
      float4 wsv = *(const float4*)(ws_ + (lane*4+q)*4);
      float4 wdv = *(const float4*)(wd_ + (lane*4+q)*4);
      float xq = (q==0) ? xv.x : (q==1) ? xv.y : (q==2) ? xv.z : xv.w;
      ps[0]+=xq*wsv.x; ps[1]+=xq*wsv.y; ps[2]+=xq*wsv.z; ps[3]+=xq*wsv.w;
      pd[0]+=xq*wdv.x; pd[1]+=xq*wdv.y; pd[2]+=xq*wdv.z; pd[3]+=xq*wdv.w;
    }
    #pragma unroll
    for (int h = 0; h < 4; h++){ ps[h] = wsum(ps[h]); pd[h] = wsum(pd[h]); }
    if (lane == 0){
      *(float4*)(asrc + (size_t)node*4) = make_float4(ps[0],ps[1],ps[2],ps[3]);
      *(float4*)(adst + (size_t)node*4) = make_float4(pd[0],pd[1],pd[2],pd[3]);
    }
  }
}

// K_C (mega, 2 rows/block): logits via asrc/adst lookup (thread-per-edge),
// softmax (8 waves = 2 rows x 4 heads), z-accum (wave halves, float4 lanes),
// gemm1+gemm2 with weight loads shared across both rows.
__global__ __launch_bounds__(512) void k_mega(const float* __restrict__ x,
    const float* __restrict__ asrc, const float* __restrict__ adst,
    const float* __restrict__ mal,
    const int* __restrict__ counts, const int* __restrict__ slist,
    const float* __restrict__ aed,
    const float* __restrict__ W, const float* __restrict__ bias,
    const float* __restrict__ fcW, const float* __restrict__ fcb,
    float* __restrict__ out){
  __shared__ float  lg[2][(CAP+1)*4];   // 4.1 KB logits/alpha per row
  __shared__ int    srcs[2][CAP+1];     // 1 KB  (srcs[r][k]=dst self-loop)
  __shared__ float4 zs4[2][256];        // 8 KB combined z per row [h*64+f4]
  __shared__ float  hsf[2][512];        // 4 KB gat row (post-lrelu)
  __shared__ float4 scratch[2048];      // 32 KB phase-aliased partials
  int rowA = blockIdx.x * 2;
  int tid = threadIdx.x;
  int lane = tid & 63, wave = tid >> 6;
  int rsel = wave >> 2;                 // attention row of this wave
  int w4 = wave & 3;                    // wave index within the row

  int kA = counts[rowA];     if (kA > CAP) kA = CAP;
  int kB = counts[rowA + 1]; if (kB > CAP) kB = CAP;
  int gA = rowA / NAG,  jA = rowA - gA*NAG;
  int dstA = gA*N2 + jA*49;
  int gB = (rowA+1) / NAG, jB = (rowA+1) - gB*NAG;
  int dstB = gB*N2 + jB*49;

  // logits: thread-per-edge, pure 16B lookups (asrc + adst + aed / mal)
  {
    int r = tid >> 8;            // 0 or 1
    int i = tid & 255;
    int kk = r ? kB : kA;
    int drow = r ? dstB : dstA;
    if (i <= kk){
      int row = rowA + r;
      int src; float4 aedv;
      if (i < kk){
        src = slist[row*CAP + i];
        aedv = *(const float4*)(aed + (size_t)(row*CAP+i)*4);
      } else {
        src = drow;
        aedv = *(const float4*)mal;
      }
      float4 as = *(const float4*)(asrc + (size_t)src*4);
      float4 ad = *(const float4*)(adst + (size_t)drow*4);
      srcs[r][i] = src;
      lg[r][i*4+0] = lrelu(as.x + ad.x + aedv.x, 0.2f);
      lg[r][i*4+1] = lrelu(as.y + ad.y + aedv.y, 0.2f);
      lg[r][i*4+2] = lrelu(as.z + ad.z + aedv.z, 0.2f);
      lg[r][i*4+3] = lrelu(as.w + ad.w + aedv.w, 0.2f);
    }
  }
  __syncthreads();

  // segment softmax: 8 waves = 2 rows x 4 heads (logits pre-activated)
  {
    int r = wave >> 2, h = wave & 3;
    int kk = r ? kB : kA;
    float m = -1e30f;
    for (int i = lane; i <= kk; i += 64) m = fmaxf(m, lg[r][i*4+h]);
    m = wmax(m);
    float s = 0.f;
    for (int i = lane; i <= kk; i += 64){
      float e = __expf(lg[r][i*4+h] - m);
      lg[r][i*4+h] = e;
      s += e;
    }
    s = wsum(s);
    float inv = 1.0f/(s + 1e-16f);
    for (int i = lane; i <= kk; i += 64) lg[r][i*4+h] *= inv;
  }
  __syncthreads();

  // z accumulation: wave handles its row's edges i = w4, w4+4, ... (incl self)
  {
    int myK = rsel ? kB : kA;
    float acc[4][4];
    #pragma unroll
    for (int h = 0; h < 4; h++)
      #pragma unroll
      for (int c = 0; c < 4; c++) acc[h][c] = 0.f;
    for (int i = w4; i <= myK; i += 4){
      int src = srcs[rsel][i];
      float4 xv = *(const float4*)(x + (size_t)src*FIN + lane*4);
      float a0 = lg[rsel][i*4+0], a1 = lg[rsel][i*4+1];
      float a2 = lg[rsel][i*4+2], a3 = lg[rsel][i*4+3];
      acc[0][0] += a0*xv.x; acc[0][1] += a0*xv.y; acc[0][2] += a0*xv.z; acc[0][3] += a0*xv.w;
      acc[1][0] += a1*xv.x; acc[1][1] += a1*xv.y; acc[1][2] += a1*xv.z; acc[1][3] += a1*xv.w;
      acc[2][0] += a2*xv.x; acc[2][1] += a2*xv.y; acc[2][2] += a2*xv.z; acc[2][3] += a2*xv.w;
      acc[3][0] += a3*xv.x; acc[3][1] += a3*xv.y; acc[3][2] += a3*xv.z; acc[3][3] += a3*xv.w;
    }
    // scratch as z-partials: [row][w4][h][lane]
    #pragma unroll
    for (int h = 0; h < 4; h++)
      scratch[rsel*1024 + w4*256 + h*64 + lane] =
        make_float4(acc[h][0], acc[h][1], acc[h][2], acc[h][3]);
  }
  __syncthreads();
  {
    // combine 4 wave-partials per row -> zs4
    int r = tid >> 8, s = tid & 255;
    float4 a = scratch[r*1024 + 0*256 + s], b = scratch[r*1024 + 1*256 + s];
    float4 c = scratch[r*1024 + 2*256 + s], d = scratch[r*1024 + 3*256 + s];
    zs4[r][s] = make_float4(a.x+b.x+c.x+d.x, a.y+b.y+c.y+d.y,
                            a.z+b.z+c.z+d.z, a.w+b.w+c.w+d.w);
  }
  __syncthreads();

  // gemm1: thread = (col-group cg 0..127 -> cols 4cg.., quarter q 0..3).
  // Each W float4 load feeds BOTH rows. 64 loads/thread.
  {
    int cg = tid & 127;
    int q  = tid >> 7;
    int h  = cg >> 5;                      // head of this col group
    const float* zA = (const float*)&zs4[0][0] + h*256 + q*64;
    const float* zB = (const float*)&zs4[1][0] + h*256 + q*64;
    const float4* Wp = (const float4*)(W + (size_t)q*64*HC) + cg;
    float4 aA = make_float4(0.f,0.f,0.f,0.f);
    float4 aB = make_float4(0.f,0.f,0.f,0.f);
    #pragma unroll 8
    for (int r = 0; r < 64; r++){
      float4 w4v = Wp[(size_t)r*(HC/4)];
      float za = zA[r], zb = zB[r];
      aA.x += za*w4v.x; aA.y += za*w4v.y; aA.z += za*w4v.z; aA.w += za*w4v.w;
      aB.x += zb*w4v.x; aB.y += zb*w4v.y; aB.z += zb*w4v.z; aB.w += zb*w4v.w;
    }
    scratch[0*512 + q*128 + cg] = aA;
    scratch[1*512 + q*128 + cg] = aB;
  }
  __syncthreads();
  if (tid < 256){
    int r = tid >> 7, cg = tid & 127;
    float4 a = scratch[r*512 + 0*128 + cg], b = scratch[r*512 + 1*128 + cg];
    float4 c = scratch[r*512 + 2*128 + cg], d = scratch[r*512 + 3*128 + cg];
    float4 bs = ((const float4*)bias)[cg];
    hsf[r][4*cg+0] = lrelu(a.x+b.x+c.x+d.x+bs.x, 0.01f);
    hsf[r][4*cg+1] = lrelu(a.y+b.y+c.y+d.y+bs.y, 0.01f);
    hsf[r][4*cg+2] = lrelu(a.z+b.z+c.z+d.z+bs.z, 0.01f);
    hsf[r][4*cg+3] = lrelu(a.w+b.w+c.w+d.w+bs.w, 0.01f);
  }
  __syncthreads();

  // gemm2: thread = (col-group cg 0..63 -> cols 4cg.., eighth e 0..7).
  // Each fcW float4 load feeds BOTH rows. 64 loads/thread.
  {
    int cg = tid & 63;
    int e  = tid >> 6;
    const float4* Fp = (const float4*)(fcW + (size_t)e*64*256) + cg;
    const float* hA = &hsf[0][0] + e*64;
    const float* hB = &hsf[1][0] + e*64;
    float4 aA = make_float4(0.f,0.f,0.f,0.f);
    float4 aB = make_float4(0.f,0.f,0.f,0.f);
    #pragma unroll 8
    for (int r = 0; r < 64; r++){
      float4 w4v = Fp[(size_t)r*64];
      float ha = hA[r], hb = hB[r];
      aA.x += ha*w4v.x; aA.y += ha*w4v.y; aA.z += ha*w4v.z; aA.w += ha*w4v.w;
      aB.x += hb*w4v.x; aB.y += hb*w4v.y; aB.z += hb*w4v.z; aB.w += hb*w4v.w;
    }
    scratch[0*512 + e*64 + cg] = aA;
    scratch[1*512 + e*64 + cg] = aB;
  }
  __syncthreads();
  if (tid < 128){
    int r = tid >> 6, cg = tid & 63;
    float4 s0 = scratch[r*512 + 0*64 + cg];
    #pragma unroll
    for (int e = 1; e < 8; e++){
      float4 t = scratch[r*512 + e*64 + cg];
      s0.x += t.x; s0.y += t.y; s0.z += t.z; s0.w += t.w;
    }
    float4 bs = ((const float4*)fcb)[cg];
    float4 o;
    o.x = lrelu(s0.x+bs.x, 0.01f);
    o.y = lrelu(s0.y+bs.y, 0.01f);
    o.z = lrelu(s0.z+bs.z, 0.01f);
    o.w = lrelu(s0.w+bs.w, 0.01f);
    *(float4*)(out + (size_t)(rowA + r)*256 + 4*cg) = o;
  }
}

extern "C" void kernel_launch(void* const* d_in, const int* in_sizes, int n_in,
                              void* d_out, int out_size, void* d_ws, size_t ws_size,
                              hipStream_t stream) {
  const float* x        = (const float*)d_in[0];
  const int*   ei       = (const int*)  d_in[1];
  const float* ea       = (const float*)d_in[2];
  // d_in[3]=num_groups, d_in[4]=agents_per_group (fixed: 12, 48)
  const float* W        = (const float*)d_in[5];
  const float* att_src  = (const float*)d_in[6];
  const float* att_dst  = (const float*)d_in[7];
  const float* W_edge   = (const float*)d_in[8];
  const float* att_edge = (const float*)d_in[9];
  const float* bias     = (const float*)d_in[10];
  const float* fcW      = (const float*)d_in[11];
  const float* fcb      = (const float*)d_in[12];
  float* out = (float*)d_out;

  float* w = (float*)d_ws;
  float*  ws_       = w;                    // 1024
  float*  wd_       = w + 1024;             // 1024
  float*  we_       = w + 2048;             // 64
  float*  easum     = w + 2112;             // 16
  int*    counts    = (int*)(w + 2128);     // 576
  float*  easum_p   = w + 2704;             // 512*16 = 8192 (16B-aligned)
  int*    slist     = (int*)(w + 10896);    // 576*128 = 73728
  float*  aed       = w + 84624;            // 576*128*4 = 294912 (16B-aligned)
  float*  asrc      = w + 379536;           // 27648*4 = 110592 (16B-aligned)
  float*  adst      = w + 490128;           // 27648*4 = 110592 (16B-aligned)
  float*  mal       = w + 600720;           // 4 (16B-aligned)

  k_pre<<<11 + MPART, 256, 0, stream>>>(W, att_src, att_dst, W_edge, att_edge, ea,
                                        ws_, wd_, we_, counts, (float4*)easum_p);
  k_scan<<<ASRCB0 + NNODES/4, 256, 0, stream>>>(ei, ea, we_, ws_, wd_, x,
                                                counts, slist, aed,
                                                easum_p, easum, mal, asrc, adst);
  k_mega<<<NOUT/2, 512, 0, stream>>>(x, asrc, adst, mal, counts, slist, aed,
                                     W, bias, fcW, fcb, out);
}

// Round 7
// 149.646 us; speedup vs baseline: 1.0268x; 1.0268x over previous
//
#include <hip/hip_runtime.h>

// Problem constants (fixed by setup_inputs)
#define NNODES 27648
#define NEDGES 442368
#define FIN    256
#define HC     512
#define NH     4
#define CDIM   128
#define NAG    48
#define NGRP   12
#define N2     2304    // 48*48
#define NOUT   576     // 12*48
#define CAP    128     // max edges kept per output row (Poisson mean ~16)
#define EDIM   16
#define MPART  512     // meansum partial blocks
#define SCANB  (NEDGES/256)   // 1728 edge-scan blocks
#define ASRCB0 (SCANB + 1)    // first asrc block in k_scan

// R7: k_mega = 4 rows/block, grid 144 (<=256 CUs) -> single block-pass.
// Previous 288-block version paid 2x block time (32 CUs ran 2 serial blocks
// while 224 idled). Weight loads now shared across 4 rows. asrc/adst logit
// tables kept from R6.

__device__ __forceinline__ float lrelu(float v, float s){ return v > 0.0f ? v : s * v; }

__device__ __forceinline__ float wsum(float v){
  #pragma unroll
  for (int off = 32; off; off >>= 1) v += __shfl_xor(v, off, 64);
  return v;
}
__device__ __forceinline__ float wmax(float v){
  #pragma unroll
  for (int off = 32; off; off >>= 1) v = fmaxf(v, __shfl_xor(v, off, 64));
  return v;
}

// K_A (fused): blocks 0..10  -> ws/wd/we precompute + zero counts
//              blocks 11..   -> edge_attr column partial sums (float4, grid-stride)
__global__ __launch_bounds__(256) void k_pre(
    const float* __restrict__ W, const float* __restrict__ att_src,
    const float* __restrict__ att_dst, const float* __restrict__ W_edge,
    const float* __restrict__ att_edge, const float* __restrict__ ea,
    float* __restrict__ ws_, float* __restrict__ wd_, float* __restrict__ we_,
    int* __restrict__ counts, float4* __restrict__ easum_part){
  int b = blockIdx.x;
  int tid = threadIdx.x;
  if (b < 11) {
    int g = b * 256 + tid;
    if (g < 1024) {
      int f = g >> 2, h = g & 3;
      const float4* wp = (const float4*)(W + f*HC + h*CDIM);
      const float4* ap = (const float4*)(att_src + h*CDIM);
      float s = 0.f;
      #pragma unroll 8
      for (int c4 = 0; c4 < CDIM/4; c4++){
        float4 wv = wp[c4], av = ap[c4];
        s += wv.x*av.x + wv.y*av.y + wv.z*av.z + wv.w*av.w;
      }
      ws_[g] = s;
    } else if (g < 2048) {
      int gg = g - 1024; int f = gg >> 2, h = gg & 3;
      const float4* wp = (const float4*)(W + f*HC + h*CDIM);
      const float4* ap = (const float4*)(att_dst + h*CDIM);
      float s = 0.f;
      #pragma unroll 8
      for (int c4 = 0; c4 < CDIM/4; c4++){
        float4 wv = wp[c4], av = ap[c4];
        s += wv.x*av.x + wv.y*av.y + wv.z*av.z + wv.w*av.w;
      }
      wd_[gg] = s;
    } else if (g < 2112) {
      int gg = g - 2048; int d = gg >> 2, h = gg & 3;
      const float4* wp = (const float4*)(W_edge + d*HC + h*CDIM);
      const float4* ap = (const float4*)(att_edge + h*CDIM);
      float s = 0.f;
      #pragma unroll 8
      for (int c4 = 0; c4 < CDIM/4; c4++){
        float4 wv = wp[c4], av = ap[c4];
        s += wv.x*av.x + wv.y*av.y + wv.z*av.z + wv.w*av.w;
      }
      we_[gg] = s;
    } else if (g < 2112 + NOUT) {
      counts[g - 2112] = 0;
    }
  } else {
    // edge_attr partial column sums; col-group = idx & 3 (invariant under stride)
    int pb = b - 11;
    const float4* p = (const float4*)ea;
    const int total = NEDGES * 4;           // float4 count
    float4 acc = make_float4(0.f, 0.f, 0.f, 0.f);
    for (int i = pb*256 + tid; i < total; i += MPART*256){
      float4 v = p[i];
      acc.x += v.x; acc.y += v.y; acc.z += v.z; acc.w += v.w;
    }
    // reduce across the 16 lanes sharing lane&3
    #pragma unroll
    for (int off = 4; off <= 32; off <<= 1){
      acc.x += __shfl_xor(acc.x, off, 64);
      acc.y += __shfl_xor(acc.y, off, 64);
      acc.z += __shfl_xor(acc.z, off, 64);
      acc.w += __shfl_xor(acc.w, off, 64);
    }
    __shared__ float4 sd4[16];
    int lane = tid & 63, wave = tid >> 6;
    if (lane < 4) sd4[wave*4 + lane] = acc;
    __syncthreads();
    if (tid < 4){
      float4 t = sd4[tid];
      float4 a = sd4[4+tid], c = sd4[8+tid], d = sd4[12+tid];
      t.x += a.x + c.x + d.x; t.y += a.y + c.y + d.y;
      t.z += a.z + c.z + d.z; t.w += a.w + c.w + d.w;
      easum_part[pb*4 + tid] = t;
    }
  }
}

// K_B (fused): blocks 0..1727   bin edges whose dst is diagonal
//              block 1728       reduce easum + compute mal (self-loop edge logit)
//              blocks 1729..    a_src/a_dst for all nodes (wave per node)
__global__ __launch_bounds__(256) void k_scan(const int* __restrict__ ei,
    const float* __restrict__ ea, const float* __restrict__ we_,
    const float* __restrict__ ws_, const float* __restrict__ wd_,
    const float* __restrict__ x,
    int* __restrict__ counts, int* __restrict__ slist, float* __restrict__ aed,
    const float* __restrict__ easum_part, float* __restrict__ easum,
    float* __restrict__ mal, float* __restrict__ asrc, float* __restrict__ adst){
  int tid = threadIdx.x;
  int b = blockIdx.x;
  if (b < SCANB){
    int e = b*256 + tid;
    int dst = ei[NEDGES + e];
    int r = dst % N2;
    if (r % 49) return;
    int row = (dst / N2) * NAG + r / 49;
    int pos = atomicAdd(&counts[row], 1);
    if (pos >= CAP) return;
    slist[row*CAP + pos] = ei[e];
    const float* eap = ea + (size_t)e*EDIM;
    float a0=0.f,a1=0.f,a2=0.f,a3=0.f;
    #pragma unroll
    for (int d = 0; d < EDIM; d++){
      float v = eap[d];
      a0 += v*we_[d*4+0]; a1 += v*we_[d*4+1]; a2 += v*we_[d*4+2]; a3 += v*we_[d*4+3];
    }
    float* ap = aed + (size_t)(row*CAP+pos)*4;
    ap[0]=a0; ap[1]=a1; ap[2]=a2; ap[3]=a3;
    return;
  }
  if (b == SCANB){
    // reduce 512 partial blocks x 16 cols -> easum[16]; then mal[4]
    int col = tid & 15, part = tid >> 4;          // 16 parts x 32 pblocks
    float s = 0.f;
    for (int pb = 0; pb < MPART/16; pb++)
      s += easum_part[(part*(MPART/16) + pb)*16 + col];
    __shared__ float sd[256];
    __shared__ float se[16];
    sd[tid] = s;
    __syncthreads();
    if (tid < 16){
      float t = 0.f;
      #pragma unroll
      for (int i = 0; i < 16; i++) t += sd[i*16 + tid];
      easum[tid] = t;
      se[tid] = t;
    }
    __syncthreads();
    if (tid < 4){
      const float invE = 1.0f/(float)NEDGES;
      float m = 0.f;
      #pragma unroll
      for (int d = 0; d < 16; d++) m += se[d]*invE*we_[d*4+tid];
      mal[tid] = m;
    }
    return;
  }
  // a_src / a_dst precompute: one wave per node, coalesced 1KB x-row read
  {
    int lane = tid & 63, wave = tid >> 6;
    int node = (b - ASRCB0)*4 + wave;
    float4 xv = *(const float4*)(x + (size_t)node*FIN + lane*4);
    float ps[4] = {0.f,0.f,0.f,0.f}, pd[4] = {0.f,0.f,0.f,0.f};
    #pragma unroll
    for (int q = 0; q < 4; q++){
      float4 wsv = *(const float4*)(ws_ + (lane*4+q)*4);
      float4 wdv = *(const float4*)(wd_ + (lane*4+q)*4);
      float xq = (q==0) ? xv.x : (q==1) ? xv.y : (q==2) ? xv.z : xv.w;
      ps[0]+=xq*wsv.x; ps[1]+=xq*wsv.y; ps[2]+=xq*wsv.z; ps[3]+=xq*wsv.w;
      pd[0]+=xq*wdv.x; pd[1]+=xq*wdv.y; pd[2]+=xq*wdv.z; pd[3]+=xq*wdv.w;
    }
    #pragma unroll
    for (int h = 0; h < 4; h++){ ps[h] = wsum(ps[h]); pd[h] = wsum(pd[h]); }
    if (lane == 0){
      *(float4*)(asrc + (size_t)node*4) = make_float4(ps[0],ps[1],ps[2],ps[3]);
      *(float4*)(adst + (size_t)node*4) = make_float4(pd[0],pd[1],pd[2],pd[3]);
    }
  }
}

// K_C (mega, 4 rows/block, 144 blocks -> single pass over 256 CUs):
// logits via asrc/adst lookup (thread-per-entry), softmax (16 tasks / 8 waves),
// z-accum (2 waves/row), gemm1+gemm2 with weight loads shared across 4 rows.
__global__ __launch_bounds__(512) void k_mega(const float* __restrict__ x,
    const float* __restrict__ asrc, const float* __restrict__ adst,
    const float* __restrict__ mal,
    const int* __restrict__ counts, const int* __restrict__ slist,
    const float* __restrict__ aed,
    const float* __restrict__ W, const float* __restrict__ bias,
    const float* __restrict__ fcW, const float* __restrict__ fcb,
    float* __restrict__ out){
  __shared__ float  lg[4][(CAP+1)*4];   // 8.3 KB logits/alpha per row
  __shared__ int    srcs[4][CAP+1];     // 2 KB  (srcs[r][k]=dst self-loop)
  __shared__ float4 zs4[4][256];        // 16 KB combined z per row [h*64+f4]
  __shared__ float  hsf[4][512];        // 8 KB gat rows (post-lrelu)
  __shared__ float4 scratch[2048];      // 32 KB phase-aliased partials
  int rowBase = blockIdx.x * 4;
  int tid = threadIdx.x;
  int lane = tid & 63, wave = tid >> 6;

  int kk[4], dsts[4];
  #pragma unroll
  for (int r = 0; r < 4; r++){
    int row = rowBase + r;
    int c = counts[row]; kk[r] = c > CAP ? CAP : c;
    int g = row / NAG, j = row - g*NAG;
    dsts[r] = g*N2 + j*49;
  }

  // logits: thread-per-entry, pure 16B lookups (asrc + adst + aed / mal)
  for (int idx = tid; idx < 4*(CAP+1); idx += 512){
    int r = idx / (CAP+1), i = idx - r*(CAP+1);
    if (i <= kk[r]){
      int row = rowBase + r;
      int src; float4 aedv;
      if (i < kk[r]){
        src = slist[row*CAP + i];
        aedv = *(const float4*)(aed + (size_t)(row*CAP+i)*4);
      } else {
        src = dsts[r];
        aedv = *(const float4*)mal;
      }
      float4 as = *(const float4*)(asrc + (size_t)src*4);
      float4 ad = *(const float4*)(adst + (size_t)dsts[r]*4);
      srcs[r][i] = src;
      lg[r][i*4+0] = lrelu(as.x + ad.x + aedv.x, 0.2f);
      lg[r][i*4+1] = lrelu(as.y + ad.y + aedv.y, 0.2f);
      lg[r][i*4+2] = lrelu(as.z + ad.z + aedv.z, 0.2f);
      lg[r][i*4+3] = lrelu(as.w + ad.w + aedv.w, 0.2f);
    }
  }
  __syncthreads();

  // segment softmax: 16 tasks (4 rows x 4 heads) over 8 waves, 2 rounds
  for (int t = wave; t < 16; t += 8){
    int r = t >> 2, h = t & 3;
    int k2 = kk[r];
    float m = -1e30f;
    for (int i = lane; i <= k2; i += 64) m = fmaxf(m, lg[r][i*4+h]);
    m = wmax(m);
    float s = 0.f;
    for (int i = lane; i <= k2; i += 64){
      float e = __expf(lg[r][i*4+h] - m);
      lg[r][i*4+h] = e;
      s += e;
    }
    s = wsum(s);
    float inv = 1.0f/(s + 1e-16f);
    for (int i = lane; i <= k2; i += 64) lg[r][i*4+h] *= inv;
  }
  __syncthreads();

  // z accumulation: 2 waves per row; wave handles edges i = w2, w2+2, ...
  {
    int r = wave >> 1, w2 = wave & 1;
    int myK = kk[r];
    float acc[4][4];
    #pragma unroll
    for (int h = 0; h < 4; h++)
      #pragma unroll
      for (int c = 0; c < 4; c++) acc[h][c] = 0.f;
    for (int i = w2; i <= myK; i += 2){
      int src = srcs[r][i];
      float4 xv = *(const float4*)(x + (size_t)src*FIN + lane*4);
      float a0 = lg[r][i*4+0], a1 = lg[r][i*4+1];
      float a2 = lg[r][i*4+2], a3 = lg[r][i*4+3];
      acc[0][0] += a0*xv.x; acc[0][1] += a0*xv.y; acc[0][2] += a0*xv.z; acc[0][3] += a0*xv.w;
      acc[1][0] += a1*xv.x; acc[1][1] += a1*xv.y; acc[1][2] += a1*xv.z; acc[1][3] += a1*xv.w;
      acc[2][0] += a2*xv.x; acc[2][1] += a2*xv.y; acc[2][2] += a2*xv.z; acc[2][3] += a2*xv.w;
      acc[3][0] += a3*xv.x; acc[3][1] += a3*xv.y; acc[3][2] += a3*xv.z; acc[3][3] += a3*xv.w;
    }
    // scratch as z-partials: [r][w2][h][lane]
    #pragma unroll
    for (int h = 0; h < 4; h++)
      scratch[r*512 + w2*256 + h*64 + lane] =
        make_float4(acc[h][0], acc[h][1], acc[h][2], acc[h][3]);
  }
  __syncthreads();
  // combine 2 wave-partials per row -> zs4 (1024 entries, 2 per thread)
  for (int f = tid; f < 1024; f += 512){
    int r = f >> 8, s = f & 255;
    float4 a = scratch[r*512 + s], b = scratch[r*512 + 256 + s];
    zs4[r][s] = make_float4(a.x+b.x, a.y+b.y, a.z+b.z, a.w+b.w);
  }
  __syncthreads();

  // gemm1: thread = (col-group cg 0..127 -> cols 4cg.., quarter q 0..3).
  // Each W float4 load feeds ALL 4 rows. 64 loads/thread.
  {
    int cg = tid & 127;
    int q  = tid >> 7;
    int h  = cg >> 5;                      // head of this col group
    const float* z0 = (const float*)&zs4[0][0] + h*256 + q*64;  // row stride 1024 floats
    const float4* Wp = (const float4*)(W + (size_t)q*64*HC) + cg;
    float4 aA = make_float4(0.f,0.f,0.f,0.f);
    float4 aB = make_float4(0.f,0.f,0.f,0.f);
    float4 aC = make_float4(0.f,0.f,0.f,0.f);
    float4 aD = make_float4(0.f,0.f,0.f,0.f);
    #pragma unroll 8
    for (int r = 0; r < 64; r++){
      float4 w4v = Wp[(size_t)r*(HC/4)];
      float za = z0[r], zb = z0[1024+r], zc = z0[2048+r], zd = z0[3072+r];
      aA.x += za*w4v.x; aA.y += za*w4v.y; aA.z += za*w4v.z; aA.w += za*w4v.w;
      aB.x += zb*w4v.x; aB.y += zb*w4v.y; aB.z += zb*w4v.z; aB.w += zb*w4v.w;
      aC.x += zc*w4v.x; aC.y += zc*w4v.y; aC.z += zc*w4v.z; aC.w += zc*w4v.w;
      aD.x += zd*w4v.x; aD.y += zd*w4v.y; aD.z += zd*w4v.z; aD.w += zd*w4v.w;
    }
    scratch[0*512 + q*128 + cg] = aA;
    scratch[1*512 + q*128 + cg] = aB;
    scratch[2*512 + q*128 + cg] = aC;
    scratch[3*512 + q*128 + cg] = aD;
  }
  __syncthreads();
  {
    int r = tid >> 7, cg = tid & 127;    // 4 rows x 128 col-groups = 512
    float4 a = scratch[r*512 + 0*128 + cg], b = scratch[r*512 + 1*128 + cg];
    float4 c = scratch[r*512 + 2*128 + cg], d = scratch[r*512 + 3*128 + cg];
    float4 bs = ((const float4*)bias)[cg];
    hsf[r][4*cg+0] = lrelu(a.x+b.x+c.x+d.x+bs.x, 0.01f);
    hsf[r][4*cg+1] = lrelu(a.y+b.y+c.y+d.y+bs.y, 0.01f);
    hsf[r][4*cg+2] = lrelu(a.z+b.z+c.z+d.z+bs.z, 0.01f);
    hsf[r][4*cg+3] = lrelu(a.w+b.w+c.w+d.w+bs.w, 0.01f);
  }
  __syncthreads();

  // gemm2: thread = (col-group cg 0..63 -> cols 4cg.., eighth e 0..7).
  // Each fcW float4 load feeds ALL 4 rows. 64 loads/thread.
  {
    int cg = tid & 63;
    int e  = tid >> 6;
    const float4* Fp = (const float4*)(fcW + (size_t)e*64*256) + cg;
    const float* h0 = &hsf[0][0] + e*64;                         // row stride 512 floats
    float4 aA = make_float4(0.f,0.f,0.f,0.f);
    float4 aB = make_float4(0.f,0.f,0.f,0.f);
    float4 aC = make_float4(0.f,0.f,0.f,0.f);
    float4 aD = make_float4(0.f,0.f,0.f,0.f);
    #pragma unroll 8
    for (int r = 0; r < 64; r++){
      float4 w4v = Fp[(size_t)r*64];
      float ha = h0[r], hb = h0[512+r], hc = h0[1024+r], hd = h0[1536+r];
      aA.x += ha*w4v.x; aA.y += ha*w4v.y; aA.z += ha*w4v.z; aA.w += ha*w4v.w;
      aB.x += hb*w4v.x; aB.y += hb*w4v.y; aB.z += hb*w4v.z; aB.w += hb*w4v.w;
      aC.x += hc*w4v.x; aC.y += hc*w4v.y; aC.z += hc*w4v.z; aC.w += hc*w4v.w;
      aD.x += hd*w4v.x; aD.y += hd*w4v.y; aD.z += hd*w4v.z; aD.w += hd*w4v.w;
    }
    scratch[0*512 + e*64 + cg] = aA;
    scratch[1*512 + e*64 + cg] = aB;
    scratch[2*512 + e*64 + cg] = aC;
    scratch[3*512 + e*64 + cg] = aD;
  }
  __syncthreads();
  if (tid < 256){
    int r = tid >> 6, cg = tid & 63;     // 4 rows x 64 col-groups
    float4 s0 = scratch[r*512 + cg];
    #pragma unroll
    for (int e = 1; e < 8; e++){
      float4 t = scratch[r*512 + e*64 + cg];
      s0.x += t.x; s0.y += t.y; s0.z += t.z; s0.w += t.w;
    }
    float4 bs = ((const float4*)fcb)[cg];
    float4 o;
    o.x = lrelu(s0.x+bs.x, 0.01f);
    o.y = lrelu(s0.y+bs.y, 0.01f);
    o.z = lrelu(s0.z+bs.z, 0.01f);
    o.w = lrelu(s0.w+bs.w, 0.01f);
    *(float4*)(out + (size_t)(rowBase + r)*256 + 4*cg) = o;
  }
}

extern "C" void kernel_launch(void* const* d_in, const int* in_sizes, int n_in,
                              void* d_out, int out_size, void* d_ws, size_t ws_size,
                              hipStream_t stream) {
  const float* x        = (const float*)d_in[0];
  const int*   ei       = (const int*)  d_in[1];
  const float* ea       = (const float*)d_in[2];
  // d_in[3]=num_groups, d_in[4]=agents_per_group (fixed: 12, 48)
  const float* W        = (const float*)d_in[5];
  const float* att_src  = (const float*)d_in[6];
  const float* att_dst  = (const float*)d_in[7];
  const float* W_edge   = (const float*)d_in[8];
  const float* att_edge = (const float*)d_in[9];
  const float* bias     = (const float*)d_in[10];
  const float* fcW      = (const float*)d_in[11];
  const float* fcb      = (const float*)d_in[12];
  float* out = (float*)d_out;

  float* w = (float*)d_ws;
  float*  ws_       = w;                    // 1024
  float*  wd_       = w + 1024;             // 1024
  float*  we_       = w + 2048;             // 64
  float*  easum     = w + 2112;             // 16
  int*    counts    = (int*)(w + 2128);     // 576
  float*  easum_p   = w + 2704;             // 512*16 = 8192 (16B-aligned)
  int*    slist     = (int*)(w + 10896);    // 576*128 = 73728
  float*  aed       = w + 84624;            // 576*128*4 = 294912 (16B-aligned)
  float*  asrc      = w + 379536;           // 27648*4 = 110592 (16B-aligned)
  float*  adst      = w + 490128;           // 27648*4 = 110592 (16B-aligned)
  float*  mal       = w + 600720;           // 4 (16B-aligned)

  k_pre<<<11 + MPART, 256, 0, stream>>>(W, att_src, att_dst, W_edge, att_edge, ea,
                                        ws_, wd_, we_, counts, (float4*)easum_p);
  k_scan<<<ASRCB0 + NNODES/4, 256, 0, stream>>>(ei, ea, we_, ws_, wd_, x,
                                                counts, slist, aed,
                                                easum_p, easum, mal, asrc, adst);
  k_mega<<<NOUT/4, 512, 0, stream>>>(x, asrc, adst, mal, counts, slist, aed,
                                     W, bias, fcW, fcb, out);
}